// Round 1
// baseline (1639.167 us; speedup 1.0000x reference)
//
#include <hip/hip_runtime.h>
#include <hip/hip_cooperative_groups.h>
#include <cstddef>

namespace cg = cooperative_groups;

#define NPTS   40000
#define NGRP   256
#define GSZ    64
#define FDIM   768
#define BATCH  2

// ---------------- FPS (farthest point sampling), exact, f64 ordering ----------------
// Cooperative kernel: 16 blocks x 1024 threads; blocks [0..7] -> batch 0, [8..15] -> batch 1.
#define FPS_BPB      8                    // blocks per batch
#define FPS_BLOCKS   (FPS_BPB * BATCH)
#define FPS_THREADS  1024
#define FPS_PPB      5000                 // points per block (8*5000 = 40000)
#define FPS_PPT      5                    // ceil(5000/1024)

// key for "max dist, tie -> min index": high 48 bits = f64 bits of dist (>=0, monotone),
// low 16 bits = (0xFFFF - idx) so larger key == smaller idx on equal dist.
__device__ __forceinline__ unsigned long long fps_key(double v, int idx) {
    unsigned long long b = (unsigned long long)__double_as_longlong(v);
    return (b & 0xFFFFFFFFFFFF0000ull) | (unsigned long long)(0xFFFFu - (unsigned)idx);
}

__global__ void __launch_bounds__(1024) fps_kernel(
    const float* __restrict__ xyz,            // (2, NPTS, 3)
    float* __restrict__ centers,              // (2, NGRP, 3)  (part of d_out)
    unsigned long long* __restrict__ partials // 2 * FPS_BLOCKS entries (double buffered)
) {
    cg::grid_group grid = cg::this_grid();
    const int blk  = blockIdx.x;
    const int b    = blk / FPS_BPB;
    const int lb   = blk % FPS_BPB;
    const int tid  = threadIdx.x;
    const int lane = tid & 63;
    const int wid  = tid >> 6;

    const float* X = xyz + (size_t)b * NPTS * 3;

    float  px[FPS_PPT], py[FPS_PPT], pz[FPS_PPT];
    double dist[FPS_PPT];
    int    gi[FPS_PPT];
#pragma unroll
    for (int j = 0; j < FPS_PPT; ++j) {
        int loc = tid + j * FPS_THREADS;
        int i   = lb * FPS_PPB + loc;
        bool ok = loc < FPS_PPB;
        gi[j]   = ok ? i : -1;
        px[j]   = ok ? X[i * 3 + 0] : 0.f;
        py[j]   = ok ? X[i * 3 + 1] : 0.f;
        pz[j]   = ok ? X[i * 3 + 2] : 0.f;
        dist[j] = 1e10;
    }

    __shared__ unsigned long long s_red[FPS_THREADS / 64];
    __shared__ float s_p[3];

    if (tid == 0) {
        float x0 = X[0], y0 = X[1], z0 = X[2];
        s_p[0] = x0; s_p[1] = y0; s_p[2] = z0;
        if (lb == 0) {
            centers[(size_t)(b * NGRP + 0) * 3 + 0] = x0;
            centers[(size_t)(b * NGRP + 0) * 3 + 1] = y0;
            centers[(size_t)(b * NGRP + 0) * 3 + 2] = z0;
        }
    }
    __syncthreads();

    for (int k = 0; k < NGRP - 1; ++k) {
        const double cx = (double)s_p[0];
        const double cy = (double)s_p[1];
        const double cz = (double)s_p[2];

        unsigned long long best = 0ull;
#pragma unroll
        for (int j = 0; j < FPS_PPT; ++j) {
            if (gi[j] >= 0) {
                double dx = (double)px[j] - cx;
                double dy = (double)py[j] - cy;
                double dz = (double)pz[j] - cz;
                double d  = dx * dx + dy * dy + dz * dz;
                double nd = dist[j] < d ? dist[j] : d;
                dist[j] = nd;
                unsigned long long key = fps_key(nd, gi[j]);
                best = key > best ? key : best;
            }
        }
        // wave max
#pragma unroll
        for (int off = 32; off >= 1; off >>= 1) {
            unsigned long long o = __shfl_xor(best, off, 64);
            best = o > best ? o : best;
        }
        if (lane == 0) s_red[wid] = best;
        __syncthreads();
        if (tid == 0) {
            unsigned long long m = s_red[0];
#pragma unroll
            for (int w = 1; w < FPS_THREADS / 64; ++w) m = s_red[w] > m ? s_red[w] : m;
            __hip_atomic_store(&partials[(k & 1) * FPS_BLOCKS + blk], m,
                               __ATOMIC_RELEASE, __HIP_MEMORY_SCOPE_AGENT);
        }
        grid.sync();
        if (tid < FPS_BPB) {
            unsigned long long m = __hip_atomic_load(
                &partials[(k & 1) * FPS_BLOCKS + b * FPS_BPB + tid],
                __ATOMIC_ACQUIRE, __HIP_MEMORY_SCOPE_AGENT);
#pragma unroll
            for (int off = 4; off >= 1; off >>= 1) {
                unsigned long long o = __shfl_xor(m, off, 64);
                m = o > m ? o : m;
            }
            if (tid == 0) {
                int widx = 0xFFFF - (int)(m & 0xFFFFull);
                float wx = X[widx * 3 + 0];
                float wy = X[widx * 3 + 1];
                float wz = X[widx * 3 + 2];
                s_p[0] = wx; s_p[1] = wy; s_p[2] = wz;
                if (lb == 0) {
                    centers[(size_t)(b * NGRP + k + 1) * 3 + 0] = wx;
                    centers[(size_t)(b * NGRP + k + 1) * 3 + 1] = wy;
                    centers[(size_t)(b * NGRP + k + 1) * 3 + 2] = wz;
                }
            }
        }
        __syncthreads();
    }
}

// ---------------- KNN (top-64 smallest dist) + feature mean + mask ----------------
// 128 blocks x 256 threads; each wave owns one center (512 centers total).
#define BC_BLOCKS 128

// key for "min dist, tie -> min index": low 16 bits = idx (within-batch, < 65536).
__device__ __forceinline__ unsigned long long knn_key(double v, int idx) {
    unsigned long long b = (unsigned long long)__double_as_longlong(v);
    return (b & 0xFFFFFFFFFFFF0000ull) | (unsigned long long)(unsigned)idx;
}

__global__ void __launch_bounds__(256) knn_agg_kernel(
    const float* __restrict__ xyz,
    const float* __restrict__ fts,
    const int*   __restrict__ valid,
    const float* __restrict__ centers,
    float* __restrict__ all_fts,
    float* __restrict__ mask)
{
    const int tid  = threadIdx.x;
    const int wid  = tid >> 6;
    const int lane = tid & 63;
    const int c    = blockIdx.x * 4 + wid;   // center id in [0, 512)
    const int b    = c >> 8;

    const float* X = xyz + (size_t)b * NPTS * 3;

    const double cx = (double)centers[(size_t)c * 3 + 0];
    const double cy = (double)centers[(size_t)c * 3 + 1];
    const double cz = (double)centers[(size_t)c * 3 + 2];

    // init slots with points 0..63
    unsigned long long slot;
    {
        float x = X[lane * 3 + 0], y = X[lane * 3 + 1], z = X[lane * 3 + 2];
        double dx = (double)x - cx, dy = (double)y - cy, dz = (double)z - cz;
        slot = knn_key(dx * dx + dy * dy + dz * dz, lane);
    }
    unsigned long long tau = slot;
#pragma unroll
    for (int off = 32; off >= 1; off >>= 1) {
        unsigned long long o = __shfl_xor(tau, off, 64);
        tau = o > tau ? o : tau;
    }

    // software-prefetched scan over remaining 624 chunks of 64 points
    float nx = X[(64 + lane) * 3 + 0];
    float ny = X[(64 + lane) * 3 + 1];
    float nz = X[(64 + lane) * 3 + 2];
    for (int s = 1; s < NPTS / 64; ++s) {
        float x = nx, y = ny, z = nz;
        if (s + 1 < NPTS / 64) {
            int i2 = (s + 1) * 64 + lane;
            nx = X[i2 * 3 + 0]; ny = X[i2 * 3 + 1]; nz = X[i2 * 3 + 2];
        }
        int i = s * 64 + lane;
        double dx = (double)x - cx, dy = (double)y - cy, dz = (double)z - cz;
        unsigned long long key = knn_key(dx * dx + dy * dy + dz * dz, i);

        unsigned long long cand = __ballot(key < tau);
        while (cand) {
            int l = __ffsll(cand) - 1;
            cand &= cand - 1;
            unsigned long long kc = __shfl(key, l, 64);
            if (kc < tau) {
                unsigned long long om = __ballot(slot == tau);
                int owner = __ffsll(om) - 1;
                if (lane == owner) slot = kc;
                unsigned long long t = slot;
#pragma unroll
                for (int off = 32; off >= 1; off >>= 1) {
                    unsigned long long o = __shfl_xor(t, off, 64);
                    t = o > t ? o : t;
                }
                tau = t;
            }
        }
    }

    __shared__ int   nbr[4][GSZ];
    __shared__ float wmask[4];
    int idx = (int)(slot & 0xFFFFull);
    nbr[wid][lane] = idx;
    int v = valid[b * NPTS + idx];
    unsigned long long vb = __ballot(v != 0);
    if (lane == 0) wmask[wid] = vb ? 1.0f : 0.0f;
    __syncthreads();

    // aggregation: 4 centers sequentially, 256 threads cover 768 dims (3 each)
    for (int cc = 0; cc < 4; ++cc) {
        int cid = blockIdx.x * 4 + cc;
        int bb  = cid >> 8;
        const float* F = fts + (size_t)bb * NPTS * FDIM;
        float a0 = 0.f, a1 = 0.f, a2 = 0.f;
        for (int j = 0; j < GSZ; ++j) {
            const float* row = F + (size_t)nbr[cc][j] * FDIM;
            a0 += row[tid];
            a1 += row[tid + 256];
            a2 += row[tid + 512];
        }
        float* o = all_fts + (size_t)cid * FDIM;
        o[tid]       = a0 * 0.015625f;   // /64
        o[tid + 256] = a1 * 0.015625f;
        o[tid + 512] = a2 * 0.015625f;
        if (tid == 0) mask[cid] = wmask[cc];
    }
}

extern "C" void kernel_launch(void* const* d_in, const int* in_sizes, int n_in,
                              void* d_out, int out_size, void* d_ws, size_t ws_size,
                              hipStream_t stream) {
    const float* xyz   = (const float*)d_in[0];
    const float* fts   = (const float*)d_in[1];
    const int*   valid = (const int*)d_in[2];

    float* out      = (float*)d_out;
    float* all_fts  = out;                                       // (2,256,768)
    float* mask     = out + (size_t)BATCH * NGRP * FDIM;         // (2,256)
    float* centers  = mask + (size_t)BATCH * NGRP;               // (2,256,3)
    unsigned long long* partials = (unsigned long long*)d_ws;    // 32 u64

    void* args[] = { (void*)&xyz, (void*)&centers, (void*)&partials };
    hipLaunchCooperativeKernel((const void*)fps_kernel,
                               dim3(FPS_BLOCKS), dim3(FPS_THREADS),
                               args, 0, stream);

    knn_agg_kernel<<<dim3(BC_BLOCKS), dim3(256), 0, stream>>>(
        xyz, fts, valid, centers, all_fts, mask);
}

// Round 2
// 988.833 us; speedup vs baseline: 1.6577x; 1.6577x over previous
//
#include <hip/hip_runtime.h>
#include <cstddef>

#define NPTS   40000
#define NGRP   256
#define GSZ    64
#define FDIM   768
#define BATCH  2

// ---------------- FPS: 16 blocks (8 per batch) x 1024 threads ----------------
// Custom per-iteration mailbox barrier in d_ws (fresh slot per iteration, no reuse).
#define FPS_BPB     8
#define FPS_BLOCKS  (FPS_BPB * BATCH)
#define FPS_THREADS 1024
#define FPS_PPB     (NPTS / FPS_BPB)   // 5000
#define FPS_PPT     5                   // ceil(5000/1024), strided, tail-guarded
#define FPS_ITERS   (NGRP - 1)

// key: high 48 bits = f64 bits of dist (>=0, monotone as integer),
// low 16 bits = 0xFFFF - idx (idx < 40000 < 65536) so larger key == smaller idx on tie.
// Key is always nonzero (0xFFFF - idx > 0 for idx <= 39999... and dist bits >= 0).
__device__ __forceinline__ unsigned long long fps_key(double v, int idx) {
    unsigned long long bits = (unsigned long long)__double_as_longlong(v);
    return (bits & 0xFFFFFFFFFFFF0000ull) | (unsigned long long)(0xFFFFu - (unsigned)idx);
}

__global__ void __launch_bounds__(FPS_THREADS, 4) fps_kernel(
    const float* __restrict__ xyz,            // (2, NPTS, 3)
    float* __restrict__ centers,              // (2, NGRP, 3) in d_out
    unsigned long long* __restrict__ keys)    // [FPS_ITERS][FPS_BLOCKS], pre-zeroed
{
    const int blk  = blockIdx.x;
    const int b    = blk >> 3;
    const int lb   = blk & 7;
    const int tid  = threadIdx.x;
    const int lane = tid & 63;
    const int wid  = tid >> 6;
    const float* __restrict__ X = xyz + (size_t)b * NPTS * 3;
    const int base = lb * FPS_PPB;

    double px[FPS_PPT], py[FPS_PPT], pz[FPS_PPT], dist[FPS_PPT];
#pragma unroll
    for (int j = 0; j < FPS_PPT; ++j) {
        int loc = tid + j * FPS_THREADS;
        bool ok = loc < FPS_PPB;
        int i   = base + (ok ? loc : 0);
        px[j]   = (double)X[i * 3 + 0];
        py[j]   = (double)X[i * 3 + 1];
        pz[j]   = (double)X[i * 3 + 2];
        dist[j] = ok ? 1e18 : -1.0;   // invalid entries stay at -1 forever (min keeps them)
    }

    __shared__ unsigned long long s_key[FPS_THREADS / 64];
    __shared__ double s_p[3];

    if (tid == 0) {
        s_p[0] = (double)X[0]; s_p[1] = (double)X[1]; s_p[2] = (double)X[2];
        if (lb == 0) {
            centers[(size_t)(b * NGRP) * 3 + 0] = X[0];
            centers[(size_t)(b * NGRP) * 3 + 1] = X[1];
            centers[(size_t)(b * NGRP) * 3 + 2] = X[2];
        }
    }
    __syncthreads();

    for (int it = 0; it < FPS_ITERS; ++it) {
        const double cx = s_p[0], cy = s_p[1], cz = s_p[2];
        double bd = -2.0; int bj = 0;
#pragma unroll
        for (int j = 0; j < FPS_PPT; ++j) {
            double dx = px[j] - cx, dy = py[j] - cy, dz = pz[j] - cz;
            double d  = fma(dz, dz, fma(dy, dy, dx * dx));
            double nd = dist[j] < d ? dist[j] : d;
            dist[j] = nd;
            if (nd > bd) { bd = nd; bj = j; }   // strict > keeps smallest j (= smallest idx)
        }
        unsigned long long key = fps_key(bd, base + tid + bj * FPS_THREADS);
#pragma unroll
        for (int off = 32; off >= 1; off >>= 1) {
            unsigned long long o = __shfl_xor(key, off, 64);
            key = o > key ? o : key;
        }
        if (lane == 0) s_key[wid] = key;
        __syncthreads();
        if (wid == 0) {
            unsigned long long k = (lane < FPS_THREADS / 64) ? s_key[lane] : 0ull;
#pragma unroll
            for (int off = 32; off >= 1; off >>= 1) {
                unsigned long long o = __shfl_xor(k, off, 64);
                k = o > k ? o : k;
            }
            if (lane == 0)
                __hip_atomic_store(&keys[it * FPS_BLOCKS + blk], k,
                                   __ATOMIC_RELEASE, __HIP_MEMORY_SCOPE_AGENT);
            // spin on this batch's 8 partials (fresh slots every iteration)
            unsigned long long pk = 0;
            if (lane < FPS_BPB) {
                const unsigned long long* slot = &keys[it * FPS_BLOCKS + b * FPS_BPB + lane];
                do {
                    pk = __hip_atomic_load(slot, __ATOMIC_ACQUIRE, __HIP_MEMORY_SCOPE_AGENT);
                } while (pk == 0ull);
            }
            unsigned long long g = pk;
#pragma unroll
            for (int off = 32; off >= 1; off >>= 1) {
                unsigned long long o = __shfl_xor(g, off, 64);
                g = o > g ? o : g;
            }
            unsigned long long wm = __ballot(lane < FPS_BPB && pk == g);
            int wl = __ffsll(wm) - 1;
            if (lane == wl) {
                int widx = 0xFFFF - (int)(g & 0xFFFFull);
                float wx = X[widx * 3 + 0], wy = X[widx * 3 + 1], wz = X[widx * 3 + 2];
                s_p[0] = (double)wx; s_p[1] = (double)wy; s_p[2] = (double)wz;
                if (lb == 0) {
                    centers[(size_t)(b * NGRP + it + 1) * 3 + 0] = wx;
                    centers[(size_t)(b * NGRP + it + 1) * 3 + 1] = wy;
                    centers[(size_t)(b * NGRP + it + 1) * 3 + 2] = wz;
                }
            }
        }
        __syncthreads();
    }
}

// ---------------- KNN: 512 blocks x 64 threads, one wave per center ----------------
__device__ __forceinline__ unsigned long long knn_key(double v, int idx) {
    unsigned long long bits = (unsigned long long)__double_as_longlong(v);
    return (bits & 0xFFFFFFFFFFFF0000ull) | (unsigned long long)(unsigned)idx;
}

__global__ void __launch_bounds__(64) knn_kernel(
    const float* __restrict__ xyz,
    const int*   __restrict__ valid,
    const float* __restrict__ centers,
    int*   __restrict__ knn_idx,
    float* __restrict__ mask)
{
    const int c    = blockIdx.x;      // [0, 512)
    const int b    = c >> 8;
    const int lane = threadIdx.x;
    const float* __restrict__ X = xyz + (size_t)b * NPTS * 3;

    const double cx = (double)centers[(size_t)c * 3 + 0];
    const double cy = (double)centers[(size_t)c * 3 + 1];
    const double cz = (double)centers[(size_t)c * 3 + 2];

    unsigned long long slot;
    {
        float x = X[lane * 3 + 0], y = X[lane * 3 + 1], z = X[lane * 3 + 2];
        double dx = (double)x - cx, dy = (double)y - cy, dz = (double)z - cz;
        slot = knn_key(dx * dx + dy * dy + dz * dz, lane);
    }
    unsigned long long tau = slot;
#pragma unroll
    for (int off = 32; off >= 1; off >>= 1) {
        unsigned long long o = __shfl_xor(tau, off, 64);
        tau = o > tau ? o : tau;
    }

    float nx = X[(64 + lane) * 3 + 0];
    float ny = X[(64 + lane) * 3 + 1];
    float nz = X[(64 + lane) * 3 + 2];
    for (int s = 1; s < NPTS / 64; ++s) {
        float x = nx, y = ny, z = nz;
        if (s + 1 < NPTS / 64) {
            int i2 = (s + 1) * 64 + lane;
            nx = X[i2 * 3 + 0]; ny = X[i2 * 3 + 1]; nz = X[i2 * 3 + 2];
        }
        int i = s * 64 + lane;
        double dx = (double)x - cx, dy = (double)y - cy, dz = (double)z - cz;
        unsigned long long key = knn_key(dx * dx + dy * dy + dz * dz, i);

        unsigned long long cand = __ballot(key < tau);
        while (cand) {
            int l = __ffsll(cand) - 1;
            cand &= cand - 1;
            unsigned long long kc = __shfl(key, l, 64);
            if (kc < tau) {
                unsigned long long om = __ballot(slot == tau);
                int owner = __ffsll(om) - 1;
                if (lane == owner) slot = kc;
                unsigned long long t = slot;
#pragma unroll
                for (int off = 32; off >= 1; off >>= 1) {
                    unsigned long long o = __shfl_xor(t, off, 64);
                    t = o > t ? o : t;
                }
                tau = t;
            }
        }
    }

    int idx = (int)(slot & 0xFFFFull);
    knn_idx[c * GSZ + lane] = idx;
    int v = valid[b * NPTS + idx];
    unsigned long long vb = __ballot(v != 0);
    if (lane == 0) mask[c] = vb ? 1.0f : 0.0f;
}

// ---------------- Aggregation: 512 blocks x 768 threads, 1 dim/thread ----------------
__global__ void __launch_bounds__(FDIM) agg_kernel(
    const float* __restrict__ fts,
    const int*   __restrict__ knn_idx,
    float* __restrict__ all_fts)
{
    const int c   = blockIdx.x;
    const int b   = c >> 8;
    const int tid = threadIdx.x;
    __shared__ int nbr[GSZ];
    if (tid < GSZ) nbr[tid] = knn_idx[c * GSZ + tid];
    __syncthreads();
    const float* __restrict__ F = fts + (size_t)b * NPTS * FDIM;
    float a0 = 0.f, a1 = 0.f, a2 = 0.f, a3 = 0.f;
#pragma unroll 2
    for (int j = 0; j < GSZ; j += 4) {
        a0 += F[(size_t)nbr[j + 0] * FDIM + tid];
        a1 += F[(size_t)nbr[j + 1] * FDIM + tid];
        a2 += F[(size_t)nbr[j + 2] * FDIM + tid];
        a3 += F[(size_t)nbr[j + 3] * FDIM + tid];
    }
    all_fts[(size_t)c * FDIM + tid] = ((a0 + a1) + (a2 + a3)) * 0.015625f;
}

extern "C" void kernel_launch(void* const* d_in, const int* in_sizes, int n_in,
                              void* d_out, int out_size, void* d_ws, size_t ws_size,
                              hipStream_t stream) {
    const float* xyz   = (const float*)d_in[0];
    const float* fts   = (const float*)d_in[1];
    const int*   valid = (const int*)d_in[2];

    float* out     = (float*)d_out;
    float* all_fts = out;                                  // (2,256,768)
    float* mask    = out + (size_t)BATCH * NGRP * FDIM;    // (2,256)
    float* centers = mask + (size_t)BATCH * NGRP;          // (2,256,3)

    unsigned long long* keys = (unsigned long long*)d_ws;              // 255*16*8 = 32640 B
    int* knn_idx = (int*)((char*)d_ws + 32768);                        // 512*64*4 = 131072 B

    // zero the mailbox (d_ws is poisoned 0xAA once and never re-poisoned; the
    // spin protocol needs zeros at the start of EVERY call, so memset on-stream).
    hipMemsetAsync(d_ws, 0, 32768, stream);

    fps_kernel<<<dim3(FPS_BLOCKS), dim3(FPS_THREADS), 0, stream>>>(xyz, centers, keys);
    knn_kernel<<<dim3(BATCH * NGRP), dim3(64), 0, stream>>>(xyz, valid, centers, knn_idx, mask);
    agg_kernel<<<dim3(BATCH * NGRP), dim3(FDIM), 0, stream>>>(fts, knn_idx, all_fts);
}

// Round 3
// 897.390 us; speedup vs baseline: 1.8266x; 1.1019x over previous
//
#include <hip/hip_runtime.h>
#include <cstddef>

#define NPTS   40000
#define NGRP   256
#define GSZ    64
#define FDIM   768
#define BATCH  2

// ---------------- FPS: 16 blocks (8 per batch) x 1024 threads ----------------
// Relaxed-atomic mailbox in d_ws: fresh slot per iteration, key IS the message
// (dist bits | idx), so no acquire/release ordering is needed anywhere.
#define FPS_BPB     8
#define FPS_BLOCKS  (FPS_BPB * BATCH)
#define FPS_THREADS 1024
#define FPS_PPB     (NPTS / FPS_BPB)   // 5000
#define FPS_PPT     5
#define FPS_ITERS   (NGRP - 1)

// key: high 48 bits = f64 bits of dist (>=0, monotone as integer),
// low 16 bits = 0xFFFF - idx so larger key == smaller idx on tie. Never zero.
__device__ __forceinline__ unsigned long long fps_key(double v, int idx) {
    unsigned long long bits = (unsigned long long)__double_as_longlong(v);
    return (bits & 0xFFFFFFFFFFFF0000ull) | (unsigned long long)(0xFFFFu - (unsigned)idx);
}

__global__ void __launch_bounds__(FPS_THREADS, 4) fps_kernel(
    const float* __restrict__ xyz,            // (2, NPTS, 3)
    float* __restrict__ centers,              // (2, NGRP, 3) in d_out
    unsigned long long* __restrict__ keys)    // [FPS_ITERS][FPS_BLOCKS], pre-zeroed
{
    const int blk  = blockIdx.x;
    const int b    = blk >> 3;
    const int lb   = blk & 7;
    const int tid  = threadIdx.x;
    const int lane = tid & 63;
    const int wid  = tid >> 6;
    const float* __restrict__ X = xyz + (size_t)b * NPTS * 3;
    const int base = lb * FPS_PPB;

    double px[FPS_PPT], py[FPS_PPT], pz[FPS_PPT], dist[FPS_PPT];
#pragma unroll
    for (int j = 0; j < FPS_PPT; ++j) {
        int loc = tid + j * FPS_THREADS;
        bool ok = loc < FPS_PPB;
        int i   = base + (ok ? loc : 0);
        px[j]   = (double)X[i * 3 + 0];
        py[j]   = (double)X[i * 3 + 1];
        pz[j]   = (double)X[i * 3 + 2];
        dist[j] = ok ? 1e18 : -1.0;   // invalid entries never win (valid dists >= 0)
    }

    __shared__ unsigned long long s_key[FPS_THREADS / 64];

    // initial center: point 0 of the batch, kept in registers by every wave
    double cx = (double)X[0], cy = (double)X[1], cz = (double)X[2];
    if (lb == 0 && tid == 0) {
        centers[(size_t)(b * NGRP) * 3 + 0] = X[0];
        centers[(size_t)(b * NGRP) * 3 + 1] = X[1];
        centers[(size_t)(b * NGRP) * 3 + 2] = X[2];
    }

    for (int it = 0; it < FPS_ITERS; ++it) {
        double bd = -2.0; int bj = 0;
#pragma unroll
        for (int j = 0; j < FPS_PPT; ++j) {
            double dx = px[j] - cx, dy = py[j] - cy, dz = pz[j] - cz;
            double d  = fma(dz, dz, fma(dy, dy, dx * dx));
            double nd = dist[j] < d ? dist[j] : d;
            dist[j] = nd;
            if (nd > bd) { bd = nd; bj = j; }   // strict > keeps smallest idx
        }
        unsigned long long key = fps_key(bd, base + tid + bj * FPS_THREADS);
#pragma unroll
        for (int off = 32; off >= 1; off >>= 1) {
            unsigned long long o = __shfl_xor(key, off, 64);
            key = o > key ? o : key;
        }
        if (lane == 0) s_key[wid] = key;
        __syncthreads();
        if (wid == 0) {
            unsigned long long k = (lane < FPS_THREADS / 64) ? s_key[lane] : 0ull;
#pragma unroll
            for (int off = 8; off >= 1; off >>= 1) {
                unsigned long long o = __shfl_xor(k, off, 64);
                k = o > k ? o : k;
            }
            if (lane == 0)
                __hip_atomic_store(&keys[it * FPS_BLOCKS + blk], k,
                                   __ATOMIC_RELAXED, __HIP_MEMORY_SCOPE_AGENT);
        }
        // every wave polls the 8 fresh slots of its batch independently
        unsigned long long pk = 0;
        if (lane < FPS_BPB) {
            const unsigned long long* slot = &keys[it * FPS_BLOCKS + b * FPS_BPB + lane];
            do {
                pk = __hip_atomic_load(slot, __ATOMIC_RELAXED, __HIP_MEMORY_SCOPE_AGENT);
            } while (pk == 0ull);
        }
        unsigned long long g = pk;
#pragma unroll
        for (int off = 4; off >= 1; off >>= 1) {
            unsigned long long o = __shfl_xor(g, off, 64);
            g = o > g ? o : g;
        }
        g = __shfl(g, 0, 64);
        int widx = 0xFFFF - (int)(g & 0xFFFFull);
        float wx = X[widx * 3 + 0], wy = X[widx * 3 + 1], wz = X[widx * 3 + 2];
        cx = (double)wx; cy = (double)wy; cz = (double)wz;
        if (lb == 0 && wid == 0 && lane == 0) {
            centers[(size_t)(b * NGRP + it + 1) * 3 + 0] = wx;
            centers[(size_t)(b * NGRP + it + 1) * 3 + 1] = wy;
            centers[(size_t)(b * NGRP + it + 1) * 3 + 2] = wz;
        }
        // no trailing barrier: the next iteration's s_key write only happens
        // after this wave observed the post, which wave0 emitted after reading
        // all s_key entries (data dependency) -> no WAR hazard.
    }
}

// ---------------- KNN: 512 blocks x 256 threads (4 waves per center) ----------------
__device__ __forceinline__ unsigned long long knn_key(double v, int idx) {
    unsigned long long bits = (unsigned long long)__double_as_longlong(v);
    return (bits & 0xFFFFFFFFFFFF0000ull) | (unsigned long long)(unsigned)idx;
}

#define NCHUNK (NPTS / 64)   // 625

__global__ void __launch_bounds__(256) knn_kernel(
    const float* __restrict__ xyz,
    const int*   __restrict__ valid,
    const float* __restrict__ centers,
    int*   __restrict__ knn_idx,
    float* __restrict__ mask)
{
    const int c    = blockIdx.x;      // [0, 512)
    const int b    = c >> 8;
    const int tid  = threadIdx.x;
    const int wid  = tid >> 6;
    const int lane = tid & 63;
    const float* __restrict__ X = xyz + (size_t)b * NPTS * 3;

    const double cx = (double)centers[(size_t)c * 3 + 0];
    const double cy = (double)centers[(size_t)c * 3 + 1];
    const double cz = (double)centers[(size_t)c * 3 + 2];

    // wave `wid` owns chunks s ≡ wid (mod 4); its first chunk seeds the slots
    unsigned long long slot;
    {
        int i = wid * 64 + lane;
        float x = X[i * 3 + 0], y = X[i * 3 + 1], z = X[i * 3 + 2];
        double dx = (double)x - cx, dy = (double)y - cy, dz = (double)z - cz;
        slot = knn_key(dx * dx + dy * dy + dz * dz, i);
    }
    unsigned long long tau = slot;
#pragma unroll
    for (int off = 32; off >= 1; off >>= 1) {
        unsigned long long o = __shfl_xor(tau, off, 64);
        tau = o > tau ? o : tau;
    }

    // depth-2 software prefetch over this wave's chunk list
    float ax = 0.f, ay = 0.f, az = 0.f, bx = 0.f, by = 0.f, bz = 0.f;
    {
        int ia = (wid + 4) * 64 + lane;
        ax = X[ia * 3 + 0]; ay = X[ia * 3 + 1]; az = X[ia * 3 + 2];
        int sb = wid + 8 < NCHUNK ? wid + 8 : NCHUNK - 1;
        int ib = sb * 64 + lane;
        bx = X[ib * 3 + 0]; by = X[ib * 3 + 1]; bz = X[ib * 3 + 2];
    }
    for (int s = wid + 4; s < NCHUNK; s += 4) {
        float x = ax, y = ay, z = az;
        ax = bx; ay = by; az = bz;
        int sp = s + 8 < NCHUNK ? s + 8 : NCHUNK - 1;
        int ip = sp * 64 + lane;
        bx = X[ip * 3 + 0]; by = X[ip * 3 + 1]; bz = X[ip * 3 + 2];

        int i = s * 64 + lane;
        double dx = (double)x - cx, dy = (double)y - cy, dz = (double)z - cz;
        unsigned long long key = knn_key(dx * dx + dy * dy + dz * dz, i);

        unsigned long long cand = __ballot(key < tau);
        while (cand) {
            int l = __ffsll(cand) - 1;
            cand &= cand - 1;
            unsigned long long kc = __shfl(key, l, 64);
            if (kc < tau) {
                unsigned long long om = __ballot(slot == tau);
                int owner = __ffsll(om) - 1;
                if (lane == owner) slot = kc;
                unsigned long long t = slot;
#pragma unroll
                for (int off = 32; off >= 1; off >>= 1) {
                    unsigned long long o = __shfl_xor(t, off, 64);
                    t = o > t ? o : t;
                }
                tau = t;
            }
        }
    }

    // merge the 4 local top-64 sets exactly: bitonic sort of 256 keys in LDS
    __shared__ unsigned long long skey[256];
    skey[tid] = slot;
    __syncthreads();
#pragma unroll
    for (int k = 2; k <= 256; k <<= 1) {
        for (int j = k >> 1; j > 0; j >>= 1) {
            int ixj = tid ^ j;
            if (ixj > tid) {
                unsigned long long a = skey[tid], bb = skey[ixj];
                bool up = ((tid & k) == 0);
                if ((a > bb) == up) { skey[tid] = bb; skey[ixj] = a; }
            }
            __syncthreads();
        }
    }

    if (wid == 0) {
        int idx = (int)(skey[lane] & 0xFFFFull);
        knn_idx[c * GSZ + lane] = idx;
        int v = valid[b * NPTS + idx];
        unsigned long long vb = __ballot(v != 0);
        if (lane == 0) mask[c] = vb ? 1.0f : 0.0f;
    }
}

// ---------------- Aggregation: 512 blocks x 768 threads, 1 dim/thread ----------------
__global__ void __launch_bounds__(FDIM) agg_kernel(
    const float* __restrict__ fts,
    const int*   __restrict__ knn_idx,
    float* __restrict__ all_fts)
{
    const int c   = blockIdx.x;
    const int b   = c >> 8;
    const int tid = threadIdx.x;
    __shared__ int nbr[GSZ];
    if (tid < GSZ) nbr[tid] = knn_idx[c * GSZ + tid];
    __syncthreads();
    const float* __restrict__ F = fts + (size_t)b * NPTS * FDIM;
    float a0 = 0.f, a1 = 0.f, a2 = 0.f, a3 = 0.f;
    float a4 = 0.f, a5 = 0.f, a6 = 0.f, a7 = 0.f;
#pragma unroll 1
    for (int j = 0; j < GSZ; j += 8) {
        a0 += F[(size_t)nbr[j + 0] * FDIM + tid];
        a1 += F[(size_t)nbr[j + 1] * FDIM + tid];
        a2 += F[(size_t)nbr[j + 2] * FDIM + tid];
        a3 += F[(size_t)nbr[j + 3] * FDIM + tid];
        a4 += F[(size_t)nbr[j + 4] * FDIM + tid];
        a5 += F[(size_t)nbr[j + 5] * FDIM + tid];
        a6 += F[(size_t)nbr[j + 6] * FDIM + tid];
        a7 += F[(size_t)nbr[j + 7] * FDIM + tid];
    }
    all_fts[(size_t)c * FDIM + tid] =
        (((a0 + a1) + (a2 + a3)) + ((a4 + a5) + (a6 + a7))) * 0.015625f;
}

extern "C" void kernel_launch(void* const* d_in, const int* in_sizes, int n_in,
                              void* d_out, int out_size, void* d_ws, size_t ws_size,
                              hipStream_t stream) {
    const float* xyz   = (const float*)d_in[0];
    const float* fts   = (const float*)d_in[1];
    const int*   valid = (const int*)d_in[2];

    float* out     = (float*)d_out;
    float* all_fts = out;                                  // (2,256,768)
    float* mask    = out + (size_t)BATCH * NGRP * FDIM;    // (2,256)
    float* centers = mask + (size_t)BATCH * NGRP;          // (2,256,3)

    unsigned long long* keys = (unsigned long long*)d_ws;  // 255*16*8 = 32640 B
    int* knn_idx = (int*)((char*)d_ws + 32768);            // 512*64*4 = 131072 B

    // mailbox must be zero at the start of EVERY call (harness never re-poisons)
    hipMemsetAsync(d_ws, 0, 32768, stream);

    fps_kernel<<<dim3(FPS_BLOCKS), dim3(FPS_THREADS), 0, stream>>>(xyz, centers, keys);
    knn_kernel<<<dim3(BATCH * NGRP), dim3(256), 0, stream>>>(xyz, valid, centers, knn_idx, mask);
    agg_kernel<<<dim3(BATCH * NGRP), dim3(FDIM), 0, stream>>>(fts, knn_idx, all_fts);
}

// Round 4
// 842.379 us; speedup vs baseline: 1.9459x; 1.0653x over previous
//
#include <hip/hip_runtime.h>
#include <cstddef>

#define NPTS   40000
#define NGRP   256
#define GSZ    64
#define FDIM   768
#define BATCH  2

// ---------------- FPS: 64 blocks (32 per batch) x 64 threads (1 wave) ----------------
// Wave-synchronous: no __syncthreads, no LDS. Relaxed-atomic mailbox in d_ws,
// fresh slot per iteration; the u64 key (dist bits | idx) IS the whole message.
#define FPS_BPB    32                  // blocks per batch
#define FPS_NBLK   (FPS_BPB * BATCH)   // 64
#define FPS_TPB    64
#define FPS_PPB    (NPTS / FPS_BPB)    // 1250
#define FPS_PPT    20                  // ceil(1250/64)
#define FPS_ITERS  (NGRP - 1)

// key: high 48 bits = f64 bits of dist (>=0, monotone as integer),
// low 16 bits = 0xFFFF - idx so larger key == smaller idx on tie. Never zero
// (idx <= 39999 -> low16 >= 25536).
__device__ __forceinline__ unsigned long long fps_key(double v, int idx) {
    unsigned long long bits = (unsigned long long)__double_as_longlong(v);
    return (bits & 0xFFFFFFFFFFFF0000ull) | (unsigned long long)(0xFFFFu - (unsigned)idx);
}

__global__ void __launch_bounds__(FPS_TPB) fps_kernel(
    const float* __restrict__ xyz,            // (2, NPTS, 3)
    float* __restrict__ centers,              // (2, NGRP, 3) in d_out
    unsigned long long* __restrict__ keys)    // [FPS_ITERS][FPS_NBLK], pre-zeroed
{
    const int blk  = blockIdx.x;
    const int b    = blk >> 5;            // / FPS_BPB
    const int lb   = blk & 31;
    const int lane = threadIdx.x;
    const float* __restrict__ X = xyz + (size_t)b * NPTS * 3;
    const int base  = lb * FPS_PPB;
    const int gbase = base + lane;

    double px[FPS_PPT], py[FPS_PPT], pz[FPS_PPT], dist[FPS_PPT];
#pragma unroll
    for (int j = 0; j < FPS_PPT; ++j) {
        int loc = lane + j * FPS_TPB;
        bool ok = loc < FPS_PPB;
        int i   = base + (ok ? loc : 0);
        px[j]   = (double)X[i * 3 + 0];
        py[j]   = (double)X[i * 3 + 1];
        pz[j]   = (double)X[i * 3 + 2];
        dist[j] = ok ? 1e18 : -1.0;   // invalid entries can never win (valid dists >= 0)
    }

    // initial center: point 0 of the batch, kept in registers by every wave
    double cx = (double)X[0], cy = (double)X[1], cz = (double)X[2];
    if (lb == 0 && lane == 0) {
        centers[(size_t)(b * NGRP) * 3 + 0] = X[0];
        centers[(size_t)(b * NGRP) * 3 + 1] = X[1];
        centers[(size_t)(b * NGRP) * 3 + 2] = X[2];
    }

    for (int it = 0; it < FPS_ITERS; ++it) {
        double bd = -2.0; int bj = 0;
#pragma unroll
        for (int j = 0; j < FPS_PPT; ++j) {
            double dx = px[j] - cx, dy = py[j] - cy, dz = pz[j] - cz;
            double d  = fma(dz, dz, fma(dy, dy, dx * dx));
            double nd = dist[j] < d ? dist[j] : d;
            dist[j] = nd;
            bool better = nd > bd;       // strict > keeps smallest j (= smallest idx)
            bd = better ? nd : bd;
            bj = better ? j  : bj;
        }
        unsigned long long key = fps_key(bd, gbase + (bj << 6));
#pragma unroll
        for (int off = 32; off >= 1; off >>= 1) {
            unsigned long long o = __shfl_xor(key, off, 64);
            key = o > key ? o : key;
        }
        if (lane == 0)
            __hip_atomic_store(&keys[it * FPS_NBLK + blk], key,
                               __ATOMIC_RELAXED, __HIP_MEMORY_SCOPE_AGENT);

        // 32 lanes poll the batch's 32 fresh slots (one coalesced load round)
        unsigned long long pk = 0;
        if (lane < FPS_BPB) {
            const unsigned long long* slot = &keys[it * FPS_NBLK + b * FPS_BPB + lane];
            do {
                pk = __hip_atomic_load(slot, __ATOMIC_RELAXED, __HIP_MEMORY_SCOPE_AGENT);
            } while (pk == 0ull);
        }
        unsigned long long g = pk;
#pragma unroll
        for (int off = 16; off >= 1; off >>= 1) {
            unsigned long long o = __shfl_xor(g, off, 64);
            g = o > g ? o : g;
        }
        g = __shfl(g, 0, 64);
        int widx = 0xFFFF - (int)(g & 0xFFFFull);
        float wx = X[widx * 3 + 0], wy = X[widx * 3 + 1], wz = X[widx * 3 + 2];
        cx = (double)wx; cy = (double)wy; cz = (double)wz;
        if (lb == 0 && lane == 0) {
            centers[(size_t)(b * NGRP + it + 1) * 3 + 0] = wx;
            centers[(size_t)(b * NGRP + it + 1) * 3 + 1] = wy;
            centers[(size_t)(b * NGRP + it + 1) * 3 + 2] = wz;
        }
    }
}

// ---------------- KNN: 512 blocks x 256 threads (4 waves per center) ----------------
__device__ __forceinline__ unsigned long long knn_key(double v, int idx) {
    unsigned long long bits = (unsigned long long)__double_as_longlong(v);
    return (bits & 0xFFFFFFFFFFFF0000ull) | (unsigned long long)(unsigned)idx;
}

#define NCHUNK (NPTS / 64)   // 625

__global__ void __launch_bounds__(256) knn_kernel(
    const float* __restrict__ xyz,
    const int*   __restrict__ valid,
    const float* __restrict__ centers,
    int*   __restrict__ knn_idx,
    float* __restrict__ mask)
{
    const int c    = blockIdx.x;      // [0, 512)
    const int b    = c >> 8;
    const int tid  = threadIdx.x;
    const int wid  = tid >> 6;
    const int lane = tid & 63;
    const float* __restrict__ X = xyz + (size_t)b * NPTS * 3;

    const double cx = (double)centers[(size_t)c * 3 + 0];
    const double cy = (double)centers[(size_t)c * 3 + 1];
    const double cz = (double)centers[(size_t)c * 3 + 2];

    // wave `wid` owns chunks s ≡ wid (mod 4); its first chunk seeds the slots
    unsigned long long slot;
    {
        int i = wid * 64 + lane;
        float x = X[i * 3 + 0], y = X[i * 3 + 1], z = X[i * 3 + 2];
        double dx = (double)x - cx, dy = (double)y - cy, dz = (double)z - cz;
        slot = knn_key(dx * dx + dy * dy + dz * dz, i);
    }
    unsigned long long tau = slot;
#pragma unroll
    for (int off = 32; off >= 1; off >>= 1) {
        unsigned long long o = __shfl_xor(tau, off, 64);
        tau = o > tau ? o : tau;
    }

    // depth-2 software prefetch over this wave's chunk list
    float ax = 0.f, ay = 0.f, az = 0.f, bx = 0.f, by = 0.f, bz = 0.f;
    {
        int ia = (wid + 4) * 64 + lane;
        ax = X[ia * 3 + 0]; ay = X[ia * 3 + 1]; az = X[ia * 3 + 2];
        int sb = wid + 8 < NCHUNK ? wid + 8 : NCHUNK - 1;
        int ib = sb * 64 + lane;
        bx = X[ib * 3 + 0]; by = X[ib * 3 + 1]; bz = X[ib * 3 + 2];
    }
    for (int s = wid + 4; s < NCHUNK; s += 4) {
        float x = ax, y = ay, z = az;
        ax = bx; ay = by; az = bz;
        int sp = s + 8 < NCHUNK ? s + 8 : NCHUNK - 1;
        int ip = sp * 64 + lane;
        bx = X[ip * 3 + 0]; by = X[ip * 3 + 1]; bz = X[ip * 3 + 2];

        int i = s * 64 + lane;
        double dx = (double)x - cx, dy = (double)y - cy, dz = (double)z - cz;
        unsigned long long key = knn_key(dx * dx + dy * dy + dz * dz, i);

        unsigned long long cand = __ballot(key < tau);
        while (cand) {
            int l = __ffsll(cand) - 1;
            cand &= cand - 1;
            unsigned long long kc = __shfl(key, l, 64);
            if (kc < tau) {
                unsigned long long om = __ballot(slot == tau);
                int owner = __ffsll(om) - 1;
                if (lane == owner) slot = kc;
                unsigned long long t = slot;
#pragma unroll
                for (int off = 32; off >= 1; off >>= 1) {
                    unsigned long long o = __shfl_xor(t, off, 64);
                    t = o > t ? o : t;
                }
                tau = t;
            }
        }
    }

    // merge the 4 local top-64 sets exactly: bitonic sort of 256 keys in LDS
    __shared__ unsigned long long skey[256];
    skey[tid] = slot;
    __syncthreads();
#pragma unroll
    for (int k = 2; k <= 256; k <<= 1) {
        for (int j = k >> 1; j > 0; j >>= 1) {
            int ixj = tid ^ j;
            if (ixj > tid) {
                unsigned long long a = skey[tid], bb = skey[ixj];
                bool up = ((tid & k) == 0);
                if ((a > bb) == up) { skey[tid] = bb; skey[ixj] = a; }
            }
            __syncthreads();
        }
    }

    if (wid == 0) {
        int idx = (int)(skey[lane] & 0xFFFFull);
        knn_idx[c * GSZ + lane] = idx;
        int v = valid[b * NPTS + idx];
        unsigned long long vb = __ballot(v != 0);
        if (lane == 0) mask[c] = vb ? 1.0f : 0.0f;
    }
}

// ---------------- Aggregation: 512 blocks x 768 threads, 1 dim/thread ----------------
__global__ void __launch_bounds__(FDIM) agg_kernel(
    const float* __restrict__ fts,
    const int*   __restrict__ knn_idx,
    float* __restrict__ all_fts)
{
    const int c   = blockIdx.x;
    const int b   = c >> 8;
    const int tid = threadIdx.x;
    __shared__ int nbr[GSZ];
    if (tid < GSZ) nbr[tid] = knn_idx[c * GSZ + tid];
    __syncthreads();
    const float* __restrict__ F = fts + (size_t)b * NPTS * FDIM;
    float a0 = 0.f, a1 = 0.f, a2 = 0.f, a3 = 0.f;
    float a4 = 0.f, a5 = 0.f, a6 = 0.f, a7 = 0.f;
#pragma unroll 1
    for (int j = 0; j < GSZ; j += 8) {
        a0 += F[(size_t)nbr[j + 0] * FDIM + tid];
        a1 += F[(size_t)nbr[j + 1] * FDIM + tid];
        a2 += F[(size_t)nbr[j + 2] * FDIM + tid];
        a3 += F[(size_t)nbr[j + 3] * FDIM + tid];
        a4 += F[(size_t)nbr[j + 4] * FDIM + tid];
        a5 += F[(size_t)nbr[j + 5] * FDIM + tid];
        a6 += F[(size_t)nbr[j + 6] * FDIM + tid];
        a7 += F[(size_t)nbr[j + 7] * FDIM + tid];
    }
    all_fts[(size_t)c * FDIM + tid] =
        (((a0 + a1) + (a2 + a3)) + ((a4 + a5) + (a6 + a7))) * 0.015625f;
}

extern "C" void kernel_launch(void* const* d_in, const int* in_sizes, int n_in,
                              void* d_out, int out_size, void* d_ws, size_t ws_size,
                              hipStream_t stream) {
    const float* xyz   = (const float*)d_in[0];
    const float* fts   = (const float*)d_in[1];
    const int*   valid = (const int*)d_in[2];

    float* out     = (float*)d_out;
    float* all_fts = out;                                  // (2,256,768)
    float* mask    = out + (size_t)BATCH * NGRP * FDIM;    // (2,256)
    float* centers = mask + (size_t)BATCH * NGRP;          // (2,256,3)

    unsigned long long* keys = (unsigned long long*)d_ws;  // 255*64*8 = 130560 B
    int* knn_idx = (int*)((char*)d_ws + 131072);           // 512*64*4 = 131072 B

    // mailbox must be zero at the start of EVERY call (harness never re-poisons)
    hipMemsetAsync(d_ws, 0, 131072, stream);

    fps_kernel<<<dim3(FPS_NBLK), dim3(FPS_TPB), 0, stream>>>(xyz, centers, keys);
    knn_kernel<<<dim3(BATCH * NGRP), dim3(256), 0, stream>>>(xyz, valid, centers, knn_idx, mask);
    agg_kernel<<<dim3(BATCH * NGRP), dim3(FDIM), 0, stream>>>(fts, knn_idx, all_fts);
}